// Round 3
// baseline (247.340 us; speedup 1.0000x reference)
//
#include <hip/hip_runtime.h>
#include <hip/hip_bf16.h>
#include <stdint.h>

typedef __bf16 bf16x8 __attribute__((ext_vector_type(8)));
typedef float floatx4 __attribute__((ext_vector_type(4)));

// ---------------------------------------------------------------------------
// convert_x: fp32 -> bf16, 8 elements per thread, exact grid (n % 8 == 0).
// ---------------------------------------------------------------------------
__global__ __launch_bounds__(256)
void convert_x(const float* __restrict__ in, __hip_bfloat16* __restrict__ outb) {
    const size_t i = ((size_t)blockIdx.x * 256 + threadIdx.x) * 8;
    const float4 a = *(const float4*)(in + i);
    const float4 b = *(const float4*)(in + i + 4);
    bf16x8 v;
    v[0] = (__bf16)a.x; v[1] = (__bf16)a.y; v[2] = (__bf16)a.z; v[3] = (__bf16)a.w;
    v[4] = (__bf16)b.x; v[5] = (__bf16)b.y; v[6] = (__bf16)b.z; v[7] = (__bf16)b.w;
    *(bf16x8*)((__bf16*)outb + i) = v;
}

// ---------------------------------------------------------------------------
// Prep: Wrot[o, d] = sum_k R[d,k] W[o,k],  R = kron(kron(K1,K2),K3)
// Three small contractions per W-row (fp32 in LDS), output bf16.
// d = (d1*8 + d2)*40 + d3 ; k = (k1*8 + k2)*40 + k3.  One block per row o.
// ---------------------------------------------------------------------------
__global__ __launch_bounds__(256)
void kron_rotate_w(const float* __restrict__ W,
                   const float* __restrict__ K1,
                   const float* __restrict__ K2,
                   const float* __restrict__ K3,
                   __hip_bfloat16* __restrict__ Wrot) {
    __shared__ float w0[1280];   // W row, then reused as stage-2 result
    __shared__ float t1[1280];
    __shared__ float k3s[1600];
    __shared__ float k2s[64];
    __shared__ float k1s[16];
    const int o   = blockIdx.x;
    const int tid = threadIdx.x;   // 256 threads

    for (int i = tid; i < 1280; i += 256) w0[i] = W[o * 1280 + i];
    for (int i = tid; i < 1600; i += 256) k3s[i] = K3[i];
    if (tid < 64) k2s[tid] = K2[tid];
    if (tid < 16) k1s[tid] = K1[tid];
    __syncthreads();

    // stage 1: t1[p*40 + d3] = sum_k3 w0[p*40 + k3] * K3[d3,k3],  p=(k1*8+k2)
    for (int i = tid; i < 1280; i += 256) {
        const int p = i / 40, d3 = i % 40;
        float acc = 0.f;
        for (int k3 = 0; k3 < 40; ++k3) acc += w0[p * 40 + k3] * k3s[d3 * 40 + k3];
        t1[i] = acc;
    }
    __syncthreads();

    // stage 2: w0[(k1*8+d2)*40 + d3] = sum_k2 t1[(k1*8+k2)*40 + d3] * K2[d2,k2]
    for (int i = tid; i < 1280; i += 256) {
        const int d3 = i % 40, pd = i / 40;
        const int k1 = pd >> 3, d2 = pd & 7;
        float acc = 0.f;
        for (int k2 = 0; k2 < 8; ++k2) acc += t1[(k1 * 8 + k2) * 40 + d3] * k2s[d2 * 8 + k2];
        w0[i] = acc;
    }
    __syncthreads();

    // stage 3: Wrot[o, (d1*8+d2)*40 + d3] = sum_k1 w0[(k1*8+d2)*40 + d3] * K1[d1,k1]
    for (int i = tid; i < 1280; i += 256) {
        const int d3 = i % 40, pd = i / 40;
        const int d1 = pd >> 3, d2 = pd & 7;
        float acc = 0.f;
        for (int k1 = 0; k1 < 4; ++k1) acc += w0[(k1 * 8 + d2) * 40 + d3] * k1s[d1 * 4 + k1];
        Wrot[(size_t)o * 1280 + i] = __float2bfloat16(acc);
    }
}

// ---------------------------------------------------------------------------
// Main GEMM: C[m,n] = sum_k A[m,k] * B[n,k]   (bf16 in, fp32 out/acc)
// 128x128 tile, 256 threads = 4 waves (2x2), each wave 64x64 via 4x4
// mfma_f32_16x16x32_bf16. BK=64. Register staging: global dwordx4 ->
// ds_write_b128, padded LDS row stride (9 granules) kills bank conflicts.
// ---------------------------------------------------------------------------
#define BM 128
#define BN 128
#define BK 64
#define LDK 9   // granules (16B) per LDS row: 8 data + 1 pad

__global__ __launch_bounds__(256)
void gemm_bt(const __hip_bfloat16* __restrict__ A,   // [M,K] bf16
             const __hip_bfloat16* __restrict__ B,   // [N,K] bf16
             float* __restrict__ C,                  // [M,N] fp32
             int M, int N, int K) {
    __shared__ bf16x8 As[BM * LDK];   // 18 KiB
    __shared__ bf16x8 Bs[BN * LDK];

    const int tid  = threadIdx.x;
    const int wave = tid >> 6;
    const int lane = tid & 63;
    const int q    = lane >> 4;      // quad index 0..3
    const int r16  = lane & 15;

    const int nTilesN = N / BN;
    const int bn = blockIdx.x % nTilesN;
    const int bm = blockIdx.x / nTilesN;
    const int tileM = bm * BM, tileN = bn * BN;
    const int wm = wave >> 1, wn = wave & 1;

    floatx4 acc[4][4];
#pragma unroll
    for (int i = 0; i < 4; ++i)
#pragma unroll
        for (int j = 0; j < 4; ++j) acc[i][j] = (floatx4){0.f, 0.f, 0.f, 0.f};

    const int row0 = tid >> 3;        // rows row0, row0+32, row0+64, row0+96
    const int slot = tid & 7;         // k-granule slot within BK window

    for (int kt = 0; kt < K; kt += BK) {
        bf16x8 areg[4], breg[4];
#pragma unroll
        for (int t = 0; t < 4; ++t) {
            const int row = t * 32 + row0;
            areg[t] = *(const bf16x8*)(A + (size_t)(tileM + row) * K + kt + slot * 8);
            breg[t] = *(const bf16x8*)(B + (size_t)(tileN + row) * K + kt + slot * 8);
        }
        __syncthreads();   // previous iteration's LDS readers done
#pragma unroll
        for (int t = 0; t < 4; ++t) {
            const int row = t * 32 + row0;
            As[row * LDK + slot] = areg[t];
            Bs[row * LDK + slot] = breg[t];
        }
        __syncthreads();

        // ---- compute: 2 k-steps of 32 ----
#pragma unroll
        for (int s = 0; s < 2; ++s) {
            bf16x8 af[4], bfr[4];
            const int kv = s * 4 + q;   // A/B operand: k = quad*8 + j (m120)
#pragma unroll
            for (int i = 0; i < 4; ++i) {
                const int m = wm * 64 + i * 16 + r16;
                af[i] = As[m * LDK + kv];
                const int n = wn * 64 + i * 16 + r16;
                bfr[i] = Bs[n * LDK + kv];
            }
#pragma unroll
            for (int i = 0; i < 4; ++i)
#pragma unroll
                for (int j = 0; j < 4; ++j)
                    acc[i][j] = __builtin_amdgcn_mfma_f32_16x16x32_bf16(
                        af[i], bfr[j], acc[i][j], 0, 0, 0);
        }
    }

    // ---- epilogue: C/D layout col=lane&15, row=quad*4+reg (m89/m91) ----
#pragma unroll
    for (int i = 0; i < 4; ++i) {
#pragma unroll
        for (int j = 0; j < 4; ++j) {
            const int col = tileN + wn * 64 + j * 16 + r16;
#pragma unroll
            for (int r = 0; r < 4; ++r) {
                const int row = tileM + wm * 64 + i * 16 + q * 4 + r;
                C[(size_t)row * N + col] = acc[i][j][r];
            }
        }
    }
}

// ---------------------------------------------------------------------------
extern "C" void kernel_launch(void* const* d_in, const int* in_sizes, int n_in,
                              void* d_out, int out_size, void* d_ws, size_t ws_size,
                              hipStream_t stream) {
    const float* x  = (const float*)d_in[0];  // [4,4096,1280] fp32
    const float* W  = (const float*)d_in[1];  // [1280,1280]  fp32
    const float* K1 = (const float*)d_in[2];  // [4,4]
    const float* K2 = (const float*)d_in[3];  // [8,8]
    const float* K3 = (const float*)d_in[4];  // [40,40]
    float* out = (float*)d_out;               // [4,4096,1280] fp32

    const int D = 1280;
    const int M = in_sizes[0] / D;            // 16384
    const int N = D, K = D;

    // ws layout: [0, M*K) bf16 x ; then [*, +N*K) bf16 Wrot
    __hip_bfloat16* x_bf   = (__hip_bfloat16*)d_ws;
    __hip_bfloat16* Wrot   = x_bf + (size_t)M * K;   // offset 41,943,040 B

    convert_x<<<(M * K) / (256 * 8), 256, 0, stream>>>(x, x_bf);
    kron_rotate_w<<<D, 256, 0, stream>>>(W, K1, K2, K3, Wrot);
    gemm_bt<<<(M / BM) * (N / BN), 256, 0, stream>>>(x_bf, Wrot, out, M, N, K);
}